// Round 4
// baseline (487.797 us; speedup 1.0000x reference)
//
#include <hip/hip_runtime.h>

// SSIM (skimage default): 7x7 uniform filter, valid crop (pad=3), sample cov.
// Images: 4096x4096 fp32, output region 4090x4090, result = mean(S) scalar.
//
// R4: back to R1's no-spill dataflow. CRITICAL: hsums writes a LOCAL h[10]
// which is then copied into the ring with compile-time indices. Passing
// ring[slot] as hsums' output pointer (R2/R3) defeats SROA and puts the
// whole ring in scratch (422-698 MB of scratch traffic, VALUBusy 8%).
// The local-h copy is free: full unroll + constant slots -> SSA renaming.
// ROWS=10 (409*10 == 4090) -> every block takes the branch-free path.
// Ring shrunk to 6 slots (new row is added before the oldest is retired,
// so only 6 rows are ever live in the ring).

#define W_IMG   4096
#define H_IMG   4096
#define OW      4090
#define OH      4090
#define ROWS    10            // output rows per block strip (divides OH)
#define NTHR    256           // threads per block
#define CPB     512           // output columns per block (2 per thread)
#define GX      8             // ceil(OW / CPB)
#define GY      409           // OH / ROWS exactly
#define NBLK    (GX * GY)     // 3272

__device__ __forceinline__ void hsums(const float* __restrict__ pO,
                                      const float* __restrict__ pT,
                                      float h[10])
{
    // load 8 consecutive floats of each image (8B-aligned: col0 is even)
    float2 a0 = *(const float2*)(pO + 0);
    float2 a1 = *(const float2*)(pO + 2);
    float2 a2 = *(const float2*)(pO + 4);
    float2 a3 = *(const float2*)(pO + 6);
    float2 b0 = *(const float2*)(pT + 0);
    float2 b1 = *(const float2*)(pT + 2);
    float2 b2 = *(const float2*)(pT + 4);
    float2 b3 = *(const float2*)(pT + 6);
    float o0=a0.x,o1=a0.y,o2=a1.x,o3=a1.y,o4=a2.x,o5=a2.y,o6=a3.x,o7=a3.y;
    float t0=b0.x,t1=b0.y,t2=b1.x,t3=b1.y,t4=b2.x,t5=b2.y,t6=b3.x,t7=b3.y;

    float so  = ((o0+o1)+(o2+o3)) + ((o4+o5)+o6);
    float st  = ((t0+t1)+(t2+t3)) + ((t4+t5)+t6);
    float soo = fmaf(o6,o6, fmaf(o5,o5, fmaf(o4,o4, fmaf(o3,o3, fmaf(o2,o2, fmaf(o1,o1, o0*o0))))));
    float stt = fmaf(t6,t6, fmaf(t5,t5, fmaf(t4,t4, fmaf(t3,t3, fmaf(t2,t2, fmaf(t1,t1, t0*t0))))));
    float sot = fmaf(o6,t6, fmaf(o5,t5, fmaf(o4,t4, fmaf(o3,t3, fmaf(o2,t2, fmaf(o1,t1, o0*t0))))));

    h[0] = so;   h[1] = (so  - o0) + o7;
    h[2] = st;   h[3] = (st  - t0) + t7;
    h[4] = soo;  h[5] = fmaf(o7,o7, soo) - o0*o0;
    h[6] = stt;  h[7] = fmaf(t7,t7, stt) - t0*t0;
    h[8] = sot;  h[9] = fmaf(o7,t7, sot) - o0*t0;
}

__device__ __forceinline__ float ssim_from(const float v[10], int px)
{
    // Normalization constants folded into the fmas.
    const float m    = 1.0f / 49.0f;
    const float m2   = m * m;
    const float covn = 49.0f / 48.0f;
    const float cm   = covn * m;      // covn/49
    const float cm2  = covn * m2;     // covn/49^2
    const float C1   = 4.0e-4f;       // (0.01*2)^2
    const float C2   = 3.6e-3f;       // (0.03*2)^2

    float so  = v[0+px], st  = v[2+px];
    float soo = v[4+px], stt = v[6+px], sot = v[8+px];

    float P  = so * st;
    float Q  = fmaf(so, so, st*st);
    float A1 = fmaf(2.0f*m2, P, C1);
    float B1 = fmaf(m2, Q, C1);
    float A2 = fmaf(2.0f*cm, sot, fmaf(-2.0f*cm2, P, C2));
    float B2 = fmaf(cm, soo + stt, fmaf(-cm2, Q, C2));
    return (A1*A2) * __builtin_amdgcn_rcpf(B1*B2);  // ~1 ulp, within tol
}

// One steady step, slot S (compile-time): new row into LOCAL h (SROA-able),
// add to window, emit 2 pixels, retire ring[S] (oldest row), store h there.
#define SSTEP(S)                                                            \
    {                                                                       \
        float h[10];                                                        \
        hsums(pO, pT, h);                                                   \
        pO += W_IMG; pT += W_IMG;                                           \
        _Pragma("unroll") for (int q = 0; q < 10; q++) v[q] += h[q];        \
        acc += ssim_from(v, 0);                                             \
        acc += ssim_from(v, 1);                                             \
        _Pragma("unroll") for (int q = 0; q < 10; q++) v[q] -= ring[S][q];  \
        _Pragma("unroll") for (int q = 0; q < 10; q++) ring[S][q] = h[q];   \
    }

__global__ __launch_bounds__(NTHR, 3)
void ssim_main(const float* __restrict__ O, const float* __restrict__ T,
               float* __restrict__ accp, unsigned* __restrict__ ctr,
               float* __restrict__ out)
{
    const int t  = threadIdx.x;
    const int c0 = blockIdx.x * CPB + 2*t;     // first of the 2 output cols
    const int r0 = blockIdx.y * ROWS;          // first output row of strip

    float acc = 0.0f;

    if (c0 < OW) {  // c0 even, OW even -> both pixels valid together
        const float* pO = O + (size_t)r0 * W_IMG + c0;
        const float* pT = T + (size_t)r0 * W_IMG + c0;

        float ring[6][10];   // 6-row delay line of horizontal sums (regs)
        float v[10];         // running vertical sums over the 7-row window
        #pragma unroll
        for (int q = 0; q < 10; q++) v[q] = 0.0f;

        // warm-up: input rows r0 .. r0+5 into slots 0..5 (local h + copy)
        #pragma unroll
        for (int i = 0; i < 6; i++) {
            float h[10];
            hsums(pO, pT, h);
            pO += W_IMG; pT += W_IMG;
            #pragma unroll
            for (int q = 0; q < 10; q++) { v[q] += h[q]; ring[i][q] = h[q]; }
        }

        // steady: exactly 10 steps, slots 0..5,0..3 — all compile-time.
        SSTEP(0) SSTEP(1) SSTEP(2) SSTEP(3) SSTEP(4)
        SSTEP(5) SSTEP(0) SSTEP(1) SSTEP(2) SSTEP(3)
    }

    // wave(64) shuffle reduction
    #pragma unroll
    for (int off = 32; off; off >>= 1) acc += __shfl_down(acc, off);

    __shared__ float wpart[NTHR / 64];
    if ((t & 63) == 0) wpart[t >> 6] = acc;
    __syncthreads();
    if (t == 0) {
        float s = 0.0f;
        #pragma unroll
        for (int w = 0; w < NTHR / 64; w++) s += wpart[w];
        atomicAdd(accp, s);               // device-scope
        __threadfence();
        unsigned prev = atomicAdd(ctr, 1u);
        if (prev == NBLK - 1) {           // last block finalizes
            __threadfence();
            float tot = atomicAdd(accp, 0.0f);   // read back the total
            out[0] = tot * (float)(1.0 / ((double)OW * (double)OH));
        }
    }
}

extern "C" void kernel_launch(void* const* d_in, const int* in_sizes, int n_in,
                              void* d_out, int out_size, void* d_ws, size_t ws_size,
                              hipStream_t stream)
{
    const float* O = (const float*)d_in[0];
    const float* T = (const float*)d_in[1];
    float* out = (float*)d_out;
    float* acc = (float*)d_ws;
    unsigned* ctr = (unsigned*)d_ws + 1;

    hipMemsetAsync(d_ws, 0, 2 * sizeof(float), stream);  // ws re-poisoned 0xAA

    dim3 grid(GX, GY);   // (8, 409) = 3272 blocks
    ssim_main<<<grid, NTHR, 0, stream>>>(O, T, acc, ctr, out);
}

// Round 5
// 243.638 us; speedup vs baseline: 2.0021x; 2.0021x over previous
//
#include <hip/hip_runtime.h>

// SSIM (skimage default): 7x7 uniform filter, valid crop (pad=3), sample cov.
// Images: 4096x4096 fp32, output region 4090x4090, result = mean(S) scalar.
//
// R5: EXACT R1 hot-loop structure (the only no-spill variant measured:
// VGPR=72, WRITE_SIZE=32KB): runtime jb-loop with guarded unroll-7 body,
// ring[7][10], local h + constant-index copy. Fully flattening the steady
// state (R2/R3/R4) makes the scheduler hoist loads across the whole strip,
// live ranges explode, and the backend spills the ring to scratch
// (422-698 MB of HBM scratch traffic, VALUBusy ~8%). DO NOT FLATTEN.
// Fix applied to R1's real problem (latency/occupancy: 1024 blocks = 4/CU,
// occ 22.7%): ROWS 32->16 => grid (8,256) = 2048 blocks = 8/CU.
// Keep: folded-constant SSIM epilogue, fused last-block finalize.

#define W_IMG   4096
#define H_IMG   4096
#define OW      4090
#define OH      4090
#define ROWS    16            // output rows per block strip
#define NTHR    256           // threads per block
#define CPB     512           // output columns per block (2 per thread)
#define GX      8             // ceil(OW / CPB)
#define GY      256           // ceil(OH / ROWS)
#define NBLK    (GX * GY)     // 2048

__device__ __forceinline__ void hsums(const float* __restrict__ pO,
                                      const float* __restrict__ pT,
                                      float h[10])
{
    // load 8 consecutive floats of each image (8B-aligned: col0 is even)
    float2 a0 = *(const float2*)(pO + 0);
    float2 a1 = *(const float2*)(pO + 2);
    float2 a2 = *(const float2*)(pO + 4);
    float2 a3 = *(const float2*)(pO + 6);
    float2 b0 = *(const float2*)(pT + 0);
    float2 b1 = *(const float2*)(pT + 2);
    float2 b2 = *(const float2*)(pT + 4);
    float2 b3 = *(const float2*)(pT + 6);
    float o0=a0.x,o1=a0.y,o2=a1.x,o3=a1.y,o4=a2.x,o5=a2.y,o6=a3.x,o7=a3.y;
    float t0=b0.x,t1=b0.y,t2=b1.x,t3=b1.y,t4=b2.x,t5=b2.y,t6=b3.x,t7=b3.y;

    float so  = ((o0+o1)+(o2+o3)) + ((o4+o5)+o6);
    float st  = ((t0+t1)+(t2+t3)) + ((t4+t5)+t6);
    float soo = fmaf(o6,o6, fmaf(o5,o5, fmaf(o4,o4, fmaf(o3,o3, fmaf(o2,o2, fmaf(o1,o1, o0*o0))))));
    float stt = fmaf(t6,t6, fmaf(t5,t5, fmaf(t4,t4, fmaf(t3,t3, fmaf(t2,t2, fmaf(t1,t1, t0*t0))))));
    float sot = fmaf(o6,t6, fmaf(o5,t5, fmaf(o4,t4, fmaf(o3,t3, fmaf(o2,t2, fmaf(o1,t1, o0*t0))))));

    h[0] = so;   h[1] = (so - o0) + o7;
    h[2] = st;   h[3] = (st - t0) + t7;
    h[4] = soo;  h[5] = fmaf(o7,o7, soo) - o0*o0;
    h[6] = stt;  h[7] = fmaf(t7,t7, stt) - t0*t0;
    h[8] = sot;  h[9] = fmaf(o7,t7, sot) - o0*t0;
}

__device__ __forceinline__ float ssim_from(const float v[10], int px)
{
    // Normalization constants folded into the fmas.
    const float m    = 1.0f / 49.0f;
    const float m2   = m * m;
    const float covn = 49.0f / 48.0f;
    const float cm   = covn * m;      // covn/49
    const float cm2  = covn * m2;     // covn/49^2
    const float C1   = 4.0e-4f;       // (0.01*2)^2
    const float C2   = 3.6e-3f;       // (0.03*2)^2

    float so  = v[0+px], st  = v[2+px];
    float soo = v[4+px], stt = v[6+px], sot = v[8+px];

    float P  = so * st;
    float Q  = fmaf(so, so, st*st);
    float A1 = fmaf(2.0f*m2, P, C1);
    float B1 = fmaf(m2, Q, C1);
    float A2 = fmaf(2.0f*cm, sot, fmaf(-2.0f*cm2, P, C2));
    float B2 = fmaf(cm, soo + stt, fmaf(-cm2, Q, C2));
    return (A1*A2) * __builtin_amdgcn_rcpf(B1*B2);  // ~1 ulp, within tol
}

__global__ __launch_bounds__(NTHR, 3)
void ssim_main(const float* __restrict__ O, const float* __restrict__ T,
               float* __restrict__ accp, unsigned* __restrict__ ctr,
               float* __restrict__ out)
{
    const int t  = threadIdx.x;
    const int c0 = blockIdx.x * CPB + 2*t;     // first of the 2 output cols
    const int r0 = blockIdx.y * ROWS;          // first output row of strip
    const int rows_in = min(ROWS, OH - r0);

    float acc = 0.0f;

    if (c0 < OW) {  // c0 even, OW even -> both pixels valid together
        const float* pO = O + (size_t)r0 * W_IMG + c0;
        const float* pT = T + (size_t)r0 * W_IMG + c0;

        float ring[7][10];   // 7-row delay line of horizontal sums (regs)
        float v[10];         // running vertical sums over the 7-row window
        #pragma unroll
        for (int q = 0; q < 10; q++) v[q] = 0.0f;

        // warm-up: input rows r0 .. r0+5 into slots 0..5
        #pragma unroll
        for (int i = 0; i < 6; i++) {
            float h[10];
            hsums(pO, pT, h);
            pO += W_IMG; pT += W_IMG;
            #pragma unroll
            for (int q = 0; q < 10; q++) { v[q] += h[q]; ring[i][q] = h[q]; }
        }

        // steady: runtime jb-loop + guarded unroll-7 body. This exact shape
        // is what keeps the ring in VGPRs (see header comment).
        for (int jb = 0; jb < ROWS; jb += 7) {
            #pragma unroll
            for (int u = 0; u < 7; u++) {
                const int j = jb + u;
                if (j < rows_in) {
                    float h[10];
                    hsums(pO, pT, h);
                    pO += W_IMG; pT += W_IMG;
                    #pragma unroll
                    for (int q = 0; q < 10; q++) v[q] += h[q];
                    acc += ssim_from(v, 0);
                    acc += ssim_from(v, 1);
                    #pragma unroll
                    for (int q = 0; q < 10; q++) {
                        v[q] -= ring[u][q];
                        ring[(u + 6) % 7][q] = h[q];
                    }
                }
            }
        }
    }

    // wave(64) shuffle reduction
    #pragma unroll
    for (int off = 32; off; off >>= 1) acc += __shfl_down(acc, off);

    __shared__ float wpart[NTHR / 64];
    if ((t & 63) == 0) wpart[t >> 6] = acc;
    __syncthreads();
    if (t == 0) {
        float s = 0.0f;
        #pragma unroll
        for (int w = 0; w < NTHR / 64; w++) s += wpart[w];
        atomicAdd(accp, s);               // device-scope
        __threadfence();
        unsigned prev = atomicAdd(ctr, 1u);
        if (prev == NBLK - 1) {           // last block finalizes
            __threadfence();
            float tot = atomicAdd(accp, 0.0f);   // read back the total
            out[0] = tot * (float)(1.0 / ((double)OW * (double)OH));
        }
    }
}

extern "C" void kernel_launch(void* const* d_in, const int* in_sizes, int n_in,
                              void* d_out, int out_size, void* d_ws, size_t ws_size,
                              hipStream_t stream)
{
    const float* O = (const float*)d_in[0];
    const float* T = (const float*)d_in[1];
    float* out = (float*)d_out;
    float* acc = (float*)d_ws;
    unsigned* ctr = (unsigned*)d_ws + 1;

    hipMemsetAsync(d_ws, 0, 2 * sizeof(float), stream);  // ws re-poisoned 0xAA

    dim3 grid(GX, GY);   // (8, 256) = 2048 blocks
    ssim_main<<<grid, NTHR, 0, stream>>>(O, T, acc, ctr, out);
}